// Round 3
// baseline (519.479 us; speedup 1.0000x reference)
//
#include <hip/hip_runtime.h>
#include <math.h>

#define EPS  1e-7f
#define MAXT 0.999999f   // 1 - 1e-6

typedef short  s16x8  __attribute__((ext_vector_type(8)));
typedef float  f32x16 __attribute__((ext_vector_type(16)));

__device__ __forceinline__ float waveRedSum(float v) {
    #pragma unroll
    for (int off = 32; off > 0; off >>= 1)
        v += __shfl_xor(v, off, 64);
    return v;
}

__device__ __forceinline__ unsigned short f2bf(float f) {
    unsigned u = __float_as_uint(f);
    u += 0x7fff + ((u >> 16) & 1);          // RNE, inputs are finite
    return (unsigned short)(u >> 16);
}

// ---------------------------------------------------------------------------
// Kernel A: v = log0( h_add( exp0( log0(x) @ embed ), embed_bias ) )
// v written as bf16 in MFMA-B packed layout: V[(k>>4)*2048 + n*16 + (k&15)]
// One wave per row; lane handles cols {2l, 2l+1}.
// ---------------------------------------------------------------------------
__global__ __launch_bounds__(256) void kA(const float* __restrict__ x,
                                          const float* __restrict__ embed,
                                          const float* __restrict__ ebias,
                                          unsigned short* __restrict__ vpack) {
    __shared__ float u[4][128];
    const int wave = threadIdx.x >> 6;
    const int lane = threadIdx.x & 63;
    const int row  = blockIdx.x * 4 + wave;
    const int c0   = lane * 2;

    const float2 xr = *(const float2*)(x + (size_t)row * 128 + c0);

    // log0(x)
    float n2 = waveRedSum(xr.x * xr.x + xr.y * xr.y);
    float n  = fmaxf(sqrtf(n2), EPS);
    float sc = atanhf(fminf(n, MAXT)) / n;
    u[wave][c0]     = xr.x * sc;
    u[wave][c0 + 1] = xr.y * sc;
    __syncthreads();

    // u @ embed
    float a0 = 0.f, a1 = 0.f;
    #pragma unroll 8
    for (int k = 0; k < 128; k++) {
        float  uk = u[wave][k];
        float2 e  = *(const float2*)(embed + (size_t)k * 128 + c0);
        a0 = fmaf(uk, e.x, a0);
        a1 = fmaf(uk, e.y, a1);
    }

    // exp0
    float np2 = waveRedSum(a0 * a0 + a1 * a1);
    float np  = fmaxf(sqrtf(np2), EPS);
    float se  = tanhf(np) / np;
    float h0 = a0 * se, h1 = a1 * se;
    float x2 = np2 * se * se;                    // |h|^2

    // h_add(h, embed_bias)
    float bx = ebias[c0], by = ebias[c0 + 1];
    float xy = waveRedSum(h0 * bx + h1 * by);
    float y2 = waveRedSum(bx * bx + by * by);
    float den = fmaxf(1.f + 2.f * xy + x2 * y2, EPS);
    float cx = 1.f + 2.f * xy + y2;
    float cy = 1.f - x2;
    float hb0 = (cx * h0 + cy * bx) / den;
    float hb1 = (cx * h1 + cy * by) / den;

    // log0(hb)
    float m2 = waveRedSum(hb0 * hb0 + hb1 * hb1);
    float m  = fmaxf(sqrtf(m2), EPS);
    float sl = atanhf(fminf(m, MAXT)) / m;
    float v0 = hb0 * sl, v1 = hb1 * sl;

    const int tbase = (row >> 4) * 2048 + (row & 15);
    vpack[tbase + c0 * 16]       = f2bf(v0);
    vpack[tbase + (c0 + 1) * 16] = f2bf(v1);
}

// ---------------------------------------------------------------------------
// Kernel B: t = adj @ v   (M=8192, N=128, K=8192), bf16 MFMA, fp32 partials.
// NO LDS, NO barriers: each wave owns 32 rows x all 128 cols (4 acc tiles).
// adj rows are used by exactly one wave, loaded dense fp32 (lanes m,m+32
// cover full 64B lines -> 16 lines/instr, optimal request density), cvt to
// bf16 in-register. B fragments from the 2MB L2-resident vpack (L1-shared
// across the block's 4 waves). K split S ways; independent waves hide HBM
// latency (no barrier vmcnt(0) drains anywhere).
// ---------------------------------------------------------------------------
__device__ __forceinline__ void kb_chunk(const float4& ca0, const float4& ca1,
                                         const unsigned short* bp,
                                         f32x16& acc0, f32x16& acc1,
                                         f32x16& acc2, f32x16& acc3) {
    s16x8 b0 = *(const s16x8*)(bp);
    s16x8 b1 = *(const s16x8*)(bp + 32 * 16);
    s16x8 b2 = *(const s16x8*)(bp + 64 * 16);
    s16x8 b3 = *(const s16x8*)(bp + 96 * 16);
    union { unsigned short u[8]; s16x8 v; } af;
    af.u[0] = f2bf(ca0.x); af.u[1] = f2bf(ca0.y);
    af.u[2] = f2bf(ca0.z); af.u[3] = f2bf(ca0.w);
    af.u[4] = f2bf(ca1.x); af.u[5] = f2bf(ca1.y);
    af.u[6] = f2bf(ca1.z); af.u[7] = f2bf(ca1.w);
    acc0 = __builtin_amdgcn_mfma_f32_32x32x16_bf16(af.v, b0, acc0, 0, 0, 0);
    acc1 = __builtin_amdgcn_mfma_f32_32x32x16_bf16(af.v, b1, acc1, 0, 0, 0);
    acc2 = __builtin_amdgcn_mfma_f32_32x32x16_bf16(af.v, b2, acc2, 0, 0, 0);
    acc3 = __builtin_amdgcn_mfma_f32_32x32x16_bf16(af.v, b3, acc3, 0, 0, 0);
}

__global__ __launch_bounds__(256) void kB(const float* __restrict__ adj,
                                          const unsigned short* __restrict__ vpack,
                                          float* __restrict__ tpart,
                                          int klen) {
    const int wave = threadIdx.x >> 6;
    const int lane = threadIdx.x & 63;
    const int rt   = blockIdx.x * 4 + wave;     // row-tile 0..255
    const int r0   = rt * 32;
    const int k0   = blockIdx.y * klen;
    float* tout    = tpart + (size_t)blockIdx.y * (8192 * 128);

    const int m  = lane & 31;                   // A row / C col within tile
    const int kh = lane >> 5;                   // k-half: k = kh*8 + j

    // A: row r0+m, 8 fp32 at k0 + kh*8 (lanes m, m+32 cover one 64B line)
    const float* aptr = adj + (size_t)(r0 + m) * 8192 + k0 + kh * 8;
    // B: packed layout base for this lane (n = nt*32 + m handled via +32*16)
    const unsigned short* bbase = vpack + (size_t)(k0 >> 4) * 2048 + m * 16 + kh * 8;

    f32x16 acc0 = {0.f}, acc1 = {0.f}, acc2 = {0.f}, acc3 = {0.f};

    const int kiters = klen >> 4;

    float4 a0 = *(const float4*)(aptr);
    float4 a1 = *(const float4*)(aptr + 4);

    for (int kt = 0; kt < kiters - 1; ++kt) {
        float4 ca0 = a0, ca1 = a1;
        aptr += 16;
        a0 = *(const float4*)(aptr);            // prefetch next chunk (HBM)
        a1 = *(const float4*)(aptr + 4);
        kb_chunk(ca0, ca1, bbase + (size_t)kt * 2048, acc0, acc1, acc2, acc3);
    }
    kb_chunk(a0, a1, bbase + (size_t)(kiters - 1) * 2048, acc0, acc1, acc2, acc3);

    // epilogue: C/D layout col=lane&31, row=(r&3)+8*(r>>2)+4*(lane>>5)
    #pragma unroll
    for (int r = 0; r < 16; ++r) {
        int row  = r0 + (r & 3) + 8 * (r >> 2) + 4 * kh;
        float* o = tout + (size_t)row * 128 + m;
        o[0]  = acc0[r];
        o[32] = acc1[r];
        o[64] = acc2[r];
        o[96] = acc3[r];
    }
}

// ---------------------------------------------------------------------------
// Kernel C: out = h_add( exp0( log0([x ; exp0(t)]) @ layer ), layer_bias )
// Sums the S partial slices of t, then one wave per row; lane = cols {2l,2l+1}.
// ---------------------------------------------------------------------------
__global__ __launch_bounds__(256) void kC(const float* __restrict__ x,
                                          const float* __restrict__ tpart,
                                          const float* __restrict__ layer,
                                          const float* __restrict__ lbias,
                                          float* __restrict__ out,
                                          int S) {
    __shared__ float w[4][256];
    const int wave = threadIdx.x >> 6;
    const int lane = threadIdx.x & 63;
    const int row  = blockIdx.x * 4 + wave;
    const int c0   = lane * 2;

    float2 tr = *(const float2*)(tpart + (size_t)row * 128 + c0);
    for (int s = 1; s < S; s++) {
        float2 p = *(const float2*)(tpart + (size_t)s * 8192 * 128 + (size_t)row * 128 + c0);
        tr.x += p.x; tr.y += p.y;
    }
    const float2 xr = *(const float2*)(x + (size_t)row * 128 + c0);

    float st = waveRedSum(tr.x * tr.x + tr.y * tr.y);   // |t|^2
    float sx = waveRedSum(xr.x * xr.x + xr.y * xr.y);   // |x|^2

    // neigh = exp0(t) = t * se
    float nt = fmaxf(sqrtf(st), EPS);
    float se = tanhf(nt) / nt;

    // w = log0([x ; neigh])  (norm over the 256-dim concat)
    float ncat2 = sx + st * se * se;
    float ncat  = fmaxf(sqrtf(ncat2), EPS);
    float sw    = atanhf(fminf(ncat, MAXT)) / ncat;
    w[wave][c0]           = xr.x * sw;
    w[wave][c0 + 1]       = xr.y * sw;
    w[wave][128 + c0]     = tr.x * se * sw;
    w[wave][128 + c0 + 1] = tr.y * se * sw;
    __syncthreads();

    // w @ layer
    float a0 = 0.f, a1 = 0.f;
    #pragma unroll 8
    for (int k = 0; k < 256; k++) {
        float  wk = w[wave][k];
        float2 e  = *(const float2*)(layer + (size_t)k * 128 + c0);
        a0 = fmaf(wk, e.x, a0);
        a1 = fmaf(wk, e.y, a1);
    }

    // exp0
    float np2 = waveRedSum(a0 * a0 + a1 * a1);
    float np  = fmaxf(sqrtf(np2), EPS);
    float so  = tanhf(np) / np;
    float o0 = a0 * so, o1 = a1 * so;
    float x2 = np2 * so * so;

    // h_add(o, layer_bias)
    float bx = lbias[c0], by = lbias[c0 + 1];
    float xy = waveRedSum(o0 * bx + o1 * by);
    float y2 = waveRedSum(bx * bx + by * by);
    float den = fmaxf(1.f + 2.f * xy + x2 * y2, EPS);
    float cx = 1.f + 2.f * xy + y2;
    float cy = 1.f - x2;

    float2 res;
    res.x = (cx * o0 + cy * bx) / den;
    res.y = (cx * o1 + cy * by) / den;
    *(float2*)(out + (size_t)row * 128 + c0) = res;
}

// ---------------------------------------------------------------------------
extern "C" void kernel_launch(void* const* d_in, const int* in_sizes, int n_in,
                              void* d_out, int out_size, void* d_ws, size_t ws_size,
                              hipStream_t stream) {
    const float* x     = (const float*)d_in[0];   // [8192,128]
    const float* adj   = (const float*)d_in[1];   // [8192,8192]
    const float* embed = (const float*)d_in[2];   // [128,128]
    const float* layer = (const float*)d_in[3];   // [256,128]
    const float* eb    = (const float*)d_in[4];   // [128]
    const float* lb    = (const float*)d_in[5];   // [128]
    float* out = (float*)d_out;

    const size_t vbytes = (size_t)8192 * 128 * 2;          // 2 MB bf16 packed
    const size_t slice  = (size_t)8192 * 128 * 4;          // 4 MB fp32 partial

    int S = 1;
    if      (ws_size >= vbytes + 16 * slice) S = 16;
    else if (ws_size >= vbytes +  8 * slice) S = 8;
    else if (ws_size >= vbytes +  4 * slice) S = 4;
    else if (ws_size >= vbytes +  2 * slice) S = 2;

    unsigned short* vpack = (unsigned short*)d_ws;
    float* tpart = (float*)((char*)d_ws + vbytes);

    kA<<<2048, 256, 0, stream>>>(x, embed, eb, vpack);
    kB<<<dim3(64, S), 256, 0, stream>>>(adj, vpack, tpart, 8192 / S);
    kC<<<2048, 256, 0, stream>>>(x, tpart, layer, lb, out, S);
}

// Round 4
// 515.263 us; speedup vs baseline: 1.0082x; 1.0082x over previous
//
#include <hip/hip_runtime.h>
#include <math.h>

#define EPS  1e-7f
#define MAXT 0.999999f   // 1 - 1e-6

typedef short  s16x8  __attribute__((ext_vector_type(8)));
typedef float  f32x16 __attribute__((ext_vector_type(16)));

__device__ __forceinline__ float waveRedSum(float v) {
    #pragma unroll
    for (int off = 32; off > 0; off >>= 1)
        v += __shfl_xor(v, off, 64);
    return v;
}

__device__ __forceinline__ unsigned short f2bf(float f) {
    unsigned u = __float_as_uint(f);
    u += 0x7fff + ((u >> 16) & 1);          // RNE, inputs are finite
    return (unsigned short)(u >> 16);
}

// ---------------------------------------------------------------------------
// Kernel A: v = log0( h_add( exp0( log0(x) @ embed ), embed_bias ) )
// v written as bf16 in MFMA-B packed layout: V[(k>>4)*2048 + n*16 + (k&15)]
// One wave per row; lane handles cols {2l, 2l+1}.
// ---------------------------------------------------------------------------
__global__ __launch_bounds__(256) void kA(const float* __restrict__ x,
                                          const float* __restrict__ embed,
                                          const float* __restrict__ ebias,
                                          unsigned short* __restrict__ vpack) {
    __shared__ float u[4][128];
    const int wave = threadIdx.x >> 6;
    const int lane = threadIdx.x & 63;
    const int row  = blockIdx.x * 4 + wave;
    const int c0   = lane * 2;

    const float2 xr = *(const float2*)(x + (size_t)row * 128 + c0);

    // log0(x)
    float n2 = waveRedSum(xr.x * xr.x + xr.y * xr.y);
    float n  = fmaxf(sqrtf(n2), EPS);
    float sc = atanhf(fminf(n, MAXT)) / n;
    u[wave][c0]     = xr.x * sc;
    u[wave][c0 + 1] = xr.y * sc;
    __syncthreads();

    // u @ embed
    float a0 = 0.f, a1 = 0.f;
    #pragma unroll 8
    for (int k = 0; k < 128; k++) {
        float  uk = u[wave][k];
        float2 e  = *(const float2*)(embed + (size_t)k * 128 + c0);
        a0 = fmaf(uk, e.x, a0);
        a1 = fmaf(uk, e.y, a1);
    }

    // exp0
    float np2 = waveRedSum(a0 * a0 + a1 * a1);
    float np  = fmaxf(sqrtf(np2), EPS);
    float se  = tanhf(np) / np;
    float h0 = a0 * se, h1 = a1 * se;
    float x2 = np2 * se * se;                    // |h|^2

    // h_add(h, embed_bias)
    float bx = ebias[c0], by = ebias[c0 + 1];
    float xy = waveRedSum(h0 * bx + h1 * by);
    float y2 = waveRedSum(bx * bx + by * by);
    float den = fmaxf(1.f + 2.f * xy + x2 * y2, EPS);
    float cx = 1.f + 2.f * xy + y2;
    float cy = 1.f - x2;
    float hb0 = (cx * h0 + cy * bx) / den;
    float hb1 = (cx * h1 + cy * by) / den;

    // log0(hb)
    float m2 = waveRedSum(hb0 * hb0 + hb1 * hb1);
    float m  = fmaxf(sqrtf(m2), EPS);
    float sl = atanhf(fminf(m, MAXT)) / m;
    float v0 = hb0 * sl, v1 = hb1 * sl;

    const int tbase = (row >> 4) * 2048 + (row & 15);
    vpack[tbase + c0 * 16]       = f2bf(v0);
    vpack[tbase + (c0 + 1) * 16] = f2bf(v1);
}

// ---------------------------------------------------------------------------
// Kernel B: t = adj @ v   (M=8192, N=128, K=8192), bf16 MFMA, fp32 partials.
// No LDS, no barriers. Wave owns 32 rows x 128 cols (4 acc tiles).
// Two fixes vs prior round:
//  (1) __launch_bounds__(256,4) caps VGPR at 128 -> 4 waves/SIMD (16/CU),
//      doubling bytes-in-flight; A-regs ping-pong via unroll, no copies.
//  (2) K-phase stagger: wave rt starts at chunk (rt*5 + y*3) mod kiters and
//      wraps. De-synchronizes the column phase across the machine so the
//      32KB-strided row reads spread over all HBM channels instead of
//      hammering the same 64B column slice chip-wide (channel hotspotting).
//      fp32 accumulation order changes; error margin is 5x, safe.
// ---------------------------------------------------------------------------
__device__ __forceinline__ void kb_chunk(const float4& ca0, const float4& ca1,
                                         const unsigned short* bp,
                                         f32x16& acc0, f32x16& acc1,
                                         f32x16& acc2, f32x16& acc3) {
    s16x8 b0 = *(const s16x8*)(bp);
    s16x8 b1 = *(const s16x8*)(bp + 32 * 16);
    s16x8 b2 = *(const s16x8*)(bp + 64 * 16);
    s16x8 b3 = *(const s16x8*)(bp + 96 * 16);
    union { unsigned short u[8]; s16x8 v; } af;
    af.u[0] = f2bf(ca0.x); af.u[1] = f2bf(ca0.y);
    af.u[2] = f2bf(ca0.z); af.u[3] = f2bf(ca0.w);
    af.u[4] = f2bf(ca1.x); af.u[5] = f2bf(ca1.y);
    af.u[6] = f2bf(ca1.z); af.u[7] = f2bf(ca1.w);
    acc0 = __builtin_amdgcn_mfma_f32_32x32x16_bf16(af.v, b0, acc0, 0, 0, 0);
    acc1 = __builtin_amdgcn_mfma_f32_32x32x16_bf16(af.v, b1, acc1, 0, 0, 0);
    acc2 = __builtin_amdgcn_mfma_f32_32x32x16_bf16(af.v, b2, acc2, 0, 0, 0);
    acc3 = __builtin_amdgcn_mfma_f32_32x32x16_bf16(af.v, b3, acc3, 0, 0, 0);
}

__global__ __launch_bounds__(256, 4) void kB(const float* __restrict__ adj,
                                             const unsigned short* __restrict__ vpack,
                                             float* __restrict__ tpart,
                                             int klen) {
    const int wave = threadIdx.x >> 6;
    const int lane = threadIdx.x & 63;
    const int rt   = blockIdx.x * 4 + wave;     // row-tile 0..255
    const int r0   = rt * 32;
    const int k0   = blockIdx.y * klen;
    float* tout    = tpart + (size_t)blockIdx.y * (8192 * 128);

    const int m  = lane & 31;                   // A row / C col within tile
    const int kh = lane >> 5;                   // k-half: k = kh*8 + j

    // A: row r0+m, 8 fp32 at column (k0 + kt*16 + kh*8)
    const float* abase = adj + (size_t)(r0 + m) * 8192 + k0 + kh * 8;
    // B: packed layout base for this lane
    const unsigned short* bbase = vpack + (size_t)(k0 >> 4) * 2048 + m * 16 + kh * 8;

    const int kiters = klen >> 4;               // 16-float chunks (pow2)
    const int phase  = (rt * 5 + blockIdx.y * 3) & (kiters - 1);

    f32x16 acc0 = {0.f}, acc1 = {0.f}, acc2 = {0.f}, acc3 = {0.f};

    int kt = phase;
    float4 a0 = *(const float4*)(abase + kt * 16);
    float4 a1 = *(const float4*)(abase + kt * 16 + 4);

    for (int it = 0; it < kiters; ++it) {
        const int ktn = (kt + 1) & (kiters - 1);
        float4 ca0 = a0, ca1 = a1;
        a0 = *(const float4*)(abase + ktn * 16);       // prefetch next chunk
        a1 = *(const float4*)(abase + ktn * 16 + 4);
        kb_chunk(ca0, ca1, bbase + (size_t)kt * 2048, acc0, acc1, acc2, acc3);
        kt = ktn;
    }

    // epilogue: C/D layout col=lane&31, row=(r&3)+8*(r>>2)+4*(lane>>5)
    #pragma unroll
    for (int r = 0; r < 16; ++r) {
        int row  = r0 + (r & 3) + 8 * (r >> 2) + 4 * kh;
        float* o = tout + (size_t)row * 128 + m;
        o[0]  = acc0[r];
        o[32] = acc1[r];
        o[64] = acc2[r];
        o[96] = acc3[r];
    }
}

// ---------------------------------------------------------------------------
// Kernel C: out = h_add( exp0( log0([x ; exp0(t)]) @ layer ), layer_bias )
// Sums the S partial slices of t, then one wave per row; lane = cols {2l,2l+1}.
// ---------------------------------------------------------------------------
__global__ __launch_bounds__(256) void kC(const float* __restrict__ x,
                                          const float* __restrict__ tpart,
                                          const float* __restrict__ layer,
                                          const float* __restrict__ lbias,
                                          float* __restrict__ out,
                                          int S) {
    __shared__ float w[4][256];
    const int wave = threadIdx.x >> 6;
    const int lane = threadIdx.x & 63;
    const int row  = blockIdx.x * 4 + wave;
    const int c0   = lane * 2;

    float2 tr = *(const float2*)(tpart + (size_t)row * 128 + c0);
    for (int s = 1; s < S; s++) {
        float2 p = *(const float2*)(tpart + (size_t)s * 8192 * 128 + (size_t)row * 128 + c0);
        tr.x += p.x; tr.y += p.y;
    }
    const float2 xr = *(const float2*)(x + (size_t)row * 128 + c0);

    float st = waveRedSum(tr.x * tr.x + tr.y * tr.y);   // |t|^2
    float sx = waveRedSum(xr.x * xr.x + xr.y * xr.y);   // |x|^2

    // neigh = exp0(t) = t * se
    float nt = fmaxf(sqrtf(st), EPS);
    float se = tanhf(nt) / nt;

    // w = log0([x ; neigh])  (norm over the 256-dim concat)
    float ncat2 = sx + st * se * se;
    float ncat  = fmaxf(sqrtf(ncat2), EPS);
    float sw    = atanhf(fminf(ncat, MAXT)) / ncat;
    w[wave][c0]           = xr.x * sw;
    w[wave][c0 + 1]       = xr.y * sw;
    w[wave][128 + c0]     = tr.x * se * sw;
    w[wave][128 + c0 + 1] = tr.y * se * sw;
    __syncthreads();

    // w @ layer
    float a0 = 0.f, a1 = 0.f;
    #pragma unroll 8
    for (int k = 0; k < 256; k++) {
        float  wk = w[wave][k];
        float2 e  = *(const float2*)(layer + (size_t)k * 128 + c0);
        a0 = fmaf(wk, e.x, a0);
        a1 = fmaf(wk, e.y, a1);
    }

    // exp0
    float np2 = waveRedSum(a0 * a0 + a1 * a1);
    float np  = fmaxf(sqrtf(np2), EPS);
    float so  = tanhf(np) / np;
    float o0 = a0 * so, o1 = a1 * so;
    float x2 = np2 * so * so;

    // h_add(o, layer_bias)
    float bx = lbias[c0], by = lbias[c0 + 1];
    float xy = waveRedSum(o0 * bx + o1 * by);
    float y2 = waveRedSum(bx * bx + by * by);
    float den = fmaxf(1.f + 2.f * xy + x2 * y2, EPS);
    float cx = 1.f + 2.f * xy + y2;
    float cy = 1.f - x2;

    float2 res;
    res.x = (cx * o0 + cy * bx) / den;
    res.y = (cx * o1 + cy * by) / den;
    *(float2*)(out + (size_t)row * 128 + c0) = res;
}

// ---------------------------------------------------------------------------
extern "C" void kernel_launch(void* const* d_in, const int* in_sizes, int n_in,
                              void* d_out, int out_size, void* d_ws, size_t ws_size,
                              hipStream_t stream) {
    const float* x     = (const float*)d_in[0];   // [8192,128]
    const float* adj   = (const float*)d_in[1];   // [8192,8192]
    const float* embed = (const float*)d_in[2];   // [128,128]
    const float* layer = (const float*)d_in[3];   // [256,128]
    const float* eb    = (const float*)d_in[4];   // [128]
    const float* lb    = (const float*)d_in[5];   // [128]
    float* out = (float*)d_out;

    const size_t vbytes = (size_t)8192 * 128 * 2;          // 2 MB bf16 packed
    const size_t slice  = (size_t)8192 * 128 * 4;          // 4 MB fp32 partial

    int S = 1;
    if      (ws_size >= vbytes + 16 * slice) S = 16;
    else if (ws_size >= vbytes +  8 * slice) S = 8;
    else if (ws_size >= vbytes +  4 * slice) S = 4;
    else if (ws_size >= vbytes +  2 * slice) S = 2;

    unsigned short* vpack = (unsigned short*)d_ws;
    float* tpart = (float*)((char*)d_ws + vbytes);

    kA<<<2048, 256, 0, stream>>>(x, embed, eb, vpack);
    kB<<<dim3(64, S), 256, 0, stream>>>(adj, vpack, tpart, 8192 / S);
    kC<<<2048, 256, 0, stream>>>(x, tpart, layer, lb, out, S);
}